// Round 6
// baseline (39748.456 us; speedup 1.0000x reference)
//
#include <hip/hip_runtime.h>
#include <hip/hip_cooperative_groups.h>
#include <math.h>

namespace cg = cooperative_groups;

#define NA 10
#define NT 65
#define NB 128
#define XDIM 2
#define YDIM 20
#define ZDIM 64
#define HDIM 256
#define RMDIM 256
#define NSTEP 64
#define TS 8
#define HR (TS + 1)
#define MAXTASK 980
#define LOG2PI 1.8378770664093453f

#define ENC_W1_S (348 * 256)
#define PRI_W1_S (346 * 256)
#define DEC_W1_S (430 * 256)
#define GRU_WIH_S (66 * 768)
#define GRU_WHH_S (256 * 768)
#define W2_S (256 * 256)
#define HEADW_S (256 * 64)

// column-major activation panels: [C][NB] per agent
#define SA (256 * NB)
#define GA (768 * NB)
#define ZA (ZDIM * NB)

static __device__ __forceinline__ float sp(float x) {
    return fmaxf(x, 0.f) + log1pf(expf(-fabsf(x)));
}
static __device__ __forceinline__ float sigm(float x) { return 1.f / (1.f + expf(-x)); }
static __device__ __forceinline__ float relu(float x) { return fmaxf(x, 0.f); }

struct Prm {
    const float* data;
    const int* macro;
    const float* eps;
    const float *enc_W1, *enc_b1, *enc_W2, *enc_b2, *encm_W, *encm_b, *encs_W, *encs_b;
    const float *pri_W1, *pri_b1, *pri_W2, *pri_b2, *prim_W, *prim_b, *pris_W, *pris_b;
    const float *dec_W1, *dec_b1, *dec_W2, *dec_b2, *decm_W, *decm_b, *decs_W, *decs_b;
    const float *gWih, *gbih, *gWhh, *gbhh;
    float *h_ring, *z_ring, *e1, *p1, *e2, *p2, *heads, *ghB, *dech1, *dech2;
    double* accd;
    float* out;
};

// ---- layer-1 family: enc1 (tile 0..7), pri1 (8..15), gh (16..39). K=256 over h_t. 800 ids.
static __device__ __forceinline__ void task_l1(const Prm& p, int id, int t, const float* h_t) {
    int tid = threadIdx.x;
    int lane = tid & 63, wv = tid >> 6;
    int a = id / 80;
    int r = id % 80;
    int b0 = (r & 1) * 64;
    int tile = r >> 1;
    int ep, c0;
    const float* Wb;
    int wld;
    if (tile < 8) {
        ep = 0; c0 = tile * 32;
        Wb = p.enc_W1 + a * ENC_W1_S + 92 * 256; wld = 256;
    } else if (tile < 16) {
        ep = 1; c0 = (tile - 8) * 32;
        Wb = p.pri_W1 + a * PRI_W1_S + 90 * 256; wld = 256;
    } else {
        ep = 2; c0 = (tile - 16) * 32;
        Wb = p.gWhh + a * GRU_WHH_S; wld = 768;
    }
    int n0u = __builtin_amdgcn_readfirstlane(c0 + wv * 8);
    int row = b0 + lane;
    const float* X = h_t + a * SA + row;
    const float* wp = Wb + n0u;
    float acc[8] = {};
#pragma unroll 8
    for (int k = 0; k < 256; ++k) {
        float xv = X[k * NB];
        const float* wr = wp + k * wld;
#pragma unroll
        for (int j = 0; j < 8; ++j) acc[j] = fmaf(xv, wr[j], acc[j]);
    }
    if (ep == 2) {
#pragma unroll
        for (int j = 0; j < 8; ++j)
            p.ghB[a * GA + (n0u + j) * NB + row] = acc[j] + p.gbhh[a * 768 + n0u + j];
    } else {
        const float* W1b = (ep == 0) ? p.enc_W1 + a * ENC_W1_S : p.pri_W1 + a * PRI_W1_S;
        const float* bb = (ep == 0) ? p.enc_b1 + a * HDIM : p.pri_b1 + a * HDIM;
        int mi = p.macro[(t * NB + row) * NA + a];
        const float* mrow = W1b + (ep == 0 ? 2 + mi : mi) * 256;
        float xv0 = 0.f, xv1 = 0.f;
        if (ep == 0) {
            xv0 = p.data[(t + 1) * (NB * YDIM) + row * YDIM + a * XDIM];
            xv1 = p.data[(t + 1) * (NB * YDIM) + row * YDIM + a * XDIM + 1];
        }
        float* outp = (ep == 0) ? p.e1 : p.p1;
#pragma unroll
        for (int j = 0; j < 8; ++j) {
            float v = acc[j] + bb[n0u + j] + mrow[n0u + j];
            if (ep == 0) v += xv0 * W1b[n0u + j] + xv1 * W1b[256 + n0u + j];
            outp[a * SA + (n0u + j) * NB + row] = relu(v);
        }
    }
}

// ---- dec1 [tD]: 160 ids.
static __device__ __forceinline__ void task_dec1(const Prm& p, int q, int tD) {
    int tid = threadIdx.x;
    int lane = tid & 63, wv = tid >> 6;
    int a = q / 16;
    int r = q % 16;
    int b0 = (r & 1) * 64;
    int c0 = (r >> 1) * 32;
    int n0u = __builtin_amdgcn_readfirstlane(c0 + wv * 8);
    int row = b0 + lane;
    const float* Wb = p.dec_W1 + a * DEC_W1_S;
    const float* wp = Wb + n0u;
    float acc[8] = {};
    const float* yrow = p.data + tD * (NB * YDIM) + row * YDIM;
#pragma unroll 4
    for (int k = 0; k < YDIM; ++k) {
        float xv = yrow[k];
        const float* wr = wp + k * 256;
#pragma unroll
        for (int j = 0; j < 8; ++j) acc[j] = fmaf(xv, wr[j], acc[j]);
    }
    const float* Xz = p.z_ring + (size_t)(tD % TS) * (NA * ZA) + a * ZA + row;
#pragma unroll 8
    for (int k = 0; k < ZDIM; ++k) {
        float xv = Xz[k * NB];
        const float* wr = wp + (110 + k) * 256;
#pragma unroll
        for (int j = 0; j < 8; ++j) acc[j] = fmaf(xv, wr[j], acc[j]);
    }
    const float* Xh = p.h_ring + (size_t)(tD % HR) * (NA * SA) + a * SA + row;
#pragma unroll 8
    for (int k = 0; k < 256; ++k) {
        float xv = Xh[k * NB];
        const float* wr = wp + (174 + k) * 256;
#pragma unroll
        for (int j = 0; j < 8; ++j) acc[j] = fmaf(xv, wr[j], acc[j]);
    }
    int mi = p.macro[(tD * NB + row) * NA + a];
    const float* mrow = Wb + (20 + mi) * 256;
    const float* bb = p.dec_b1 + a * HDIM;
    float* ob = p.dech1 + a * SA + row;
#pragma unroll
    for (int j = 0; j < 8; ++j)
        ob[(n0u + j) * NB] = relu(acc[j] + bb[n0u + j] + mrow[n0u + j]);
}

// ---- recon epilogue [tE]: 20 ids, uses LDS Ls + wave reduce.
static __device__ __forceinline__ void task_epi(const Prm& p, int q, int tE, float* Ls) {
    int tid = threadIdx.x;
    int lane = tid & 63, wv = tid >> 6;
    int a = q >> 1;
    int b0 = (q & 1) * 64;
    int row = b0 + lane;
    const float* d2 = p.dech2 + a * SA;
    const float* wm = p.decm_W + a * (HDIM * XDIM);
    const float* ws = p.decs_W + a * (HDIM * XDIM);
    float m0 = 0.f, m1 = 0.f, s0 = 0.f, s1 = 0.f;
#pragma unroll 8
    for (int kk = 0; kk < 64; ++kk) {
        int k = wv * 64 + kk;
        float xv = d2[k * NB + row];
        m0 = fmaf(xv, wm[k * 2], m0);
        m1 = fmaf(xv, wm[k * 2 + 1], m1);
        s0 = fmaf(xv, ws[k * 2], s0);
        s1 = fmaf(xv, ws[k * 2 + 1], s1);
    }
    Ls[(wv * 4 + 0) * 64 + lane] = m0;
    Ls[(wv * 4 + 1) * 64 + lane] = m1;
    Ls[(wv * 4 + 2) * 64 + lane] = s0;
    Ls[(wv * 4 + 3) * 64 + lane] = s1;
    __syncthreads();
    if (wv == 0) {
        float M0 = Ls[0 * 64 + lane] + Ls[4 * 64 + lane] + Ls[8 * 64 + lane] + Ls[12 * 64 + lane];
        float M1 = Ls[1 * 64 + lane] + Ls[5 * 64 + lane] + Ls[9 * 64 + lane] + Ls[13 * 64 + lane];
        float S0 = Ls[2 * 64 + lane] + Ls[6 * 64 + lane] + Ls[10 * 64 + lane] + Ls[14 * 64 + lane];
        float S1 = Ls[3 * 64 + lane] + Ls[7 * 64 + lane] + Ls[11 * 64 + lane] + Ls[15 * 64 + lane];
        float dm0 = M0 + p.decm_b[a * 2 + 0];
        float dm1 = M1 + p.decm_b[a * 2 + 1];
        float ds0 = sp(S0 + p.decs_b[a * 2 + 0]);
        float ds1 = sp(S1 + p.decs_b[a * 2 + 1]);
        int targ = tE + 1;
        float x0 = p.data[targ * (NB * YDIM) + row * YDIM + a * XDIM + 0];
        float x1 = p.data[targ * (NB * YDIM) + row * YDIM + a * XDIM + 1];
        float r0 = (x0 - dm0) / ds0, r1 = (x1 - dm1) / ds1;
        float tt = 0.5f * r0 * r0 + logf(ds0) + 0.5f * LOG2PI + 0.5f * r1 * r1 + logf(ds1) +
                   0.5f * LOG2PI;
#pragma unroll
        for (int off = 32; off > 0; off >>= 1) tt += __shfl_down(tt, off, 64);
        if (lane == 0) atomicAdd(&p.accd[0], (double)tt);
    }
    __syncthreads();
}

// ---- layer-2 family: enc2 (0..159), pri2 (160..319). K=256.
static __device__ __forceinline__ void task_l2(const Prm& p, int id) {
    int tid = threadIdx.x;
    int lane = tid & 63, wv = tid >> 6;
    int isenc = (id < 160);
    int q = isenc ? id : id - 160;
    int a = q / 16;
    int r = q % 16;
    int b0 = (r & 1) * 64;
    int c0 = (r >> 1) * 32;
    int n0u = __builtin_amdgcn_readfirstlane(c0 + wv * 8);
    int row = b0 + lane;
    const float* X = (isenc ? p.e1 : p.p1) + a * SA + row;
    const float* wp = (isenc ? p.enc_W2 : p.pri_W2) + a * W2_S + n0u;
    const float* bb = (isenc ? p.enc_b2 : p.pri_b2) + a * HDIM;
    float acc[8] = {};
#pragma unroll 8
    for (int k = 0; k < 256; ++k) {
        float xv = X[k * NB];
        const float* wr = wp + k * 256;
#pragma unroll
        for (int j = 0; j < 8; ++j) acc[j] = fmaf(xv, wr[j], acc[j]);
    }
    float* outp = isenc ? p.e2 : p.p2;
#pragma unroll
    for (int j = 0; j < 8; ++j)
        outp[a * SA + (n0u + j) * NB + row] = relu(acc[j] + bb[n0u + j]);
}

// ---- dec2 [current dech1 -> dech2]: 160 ids.
static __device__ __forceinline__ void task_dec2(const Prm& p, int q) {
    int tid = threadIdx.x;
    int lane = tid & 63, wv = tid >> 6;
    int a = q / 16;
    int r = q % 16;
    int b0 = (r & 1) * 64;
    int c0 = (r >> 1) * 32;
    int n0u = __builtin_amdgcn_readfirstlane(c0 + wv * 8);
    int row = b0 + lane;
    const float* X = p.dech1 + a * SA + row;
    const float* wp = p.dec_W2 + a * W2_S + n0u;
    const float* bb = p.dec_b2 + a * HDIM;
    float acc[8] = {};
#pragma unroll 8
    for (int k = 0; k < 256; ++k) {
        float xv = X[k * NB];
        const float* wr = wp + k * 256;
#pragma unroll
        for (int j = 0; j < 8; ++j) acc[j] = fmaf(xv, wr[j], acc[j]);
    }
    float* ob = p.dech2 + a * SA + row;
#pragma unroll
    for (int j = 0; j < 8; ++j)
        ob[(n0u + j) * NB] = relu(acc[j] + bb[n0u + j]);
}

// ---- heads: 160 ids: (a, btile, head, colhalf). K=256, 8 cols/wave.
static __device__ __forceinline__ void task_heads(const Prm& p, int id) {
    int tid = threadIdx.x;
    int lane = tid & 63, wv = tid >> 6;
    int a = id / 16;
    int r = id % 16;
    int b0 = (r & 1) * 64;
    int hc = r >> 1;
    int head = hc >> 1, c0 = (hc & 1) * 32;
    const float* Wt;
    const float* Bt;
    if (head == 0) { Wt = p.encm_W; Bt = p.encm_b; }
    else if (head == 1) { Wt = p.encs_W; Bt = p.encs_b; }
    else if (head == 2) { Wt = p.prim_W; Bt = p.prim_b; }
    else { Wt = p.pris_W; Bt = p.pris_b; }
    int n0u = __builtin_amdgcn_readfirstlane(c0 + wv * 8);
    int row = b0 + lane;
    const float* X = (head < 2 ? p.e2 : p.p2) + a * SA + row;
    const float* wp = Wt + a * HEADW_S + n0u;
    float acc[8] = {};
#pragma unroll 8
    for (int k = 0; k < 256; ++k) {
        float xv = X[k * NB];
        const float* wr = wp + k * ZDIM;
#pragma unroll
        for (int j = 0; j < 8; ++j) acc[j] = fmaf(xv, wr[j], acc[j]);
    }
#pragma unroll
    for (int j = 0; j < 8; ++j)
        p.heads[a * SA + (head * 64 + n0u + j) * NB + row] = acc[j] + Bt[a * ZDIM + n0u + j];
}

// ---- P4: z(+z_ring write, KL) staged in LDS, gi (K=64), GRU combine. 160 ids.
static __device__ __forceinline__ void task_p4(const Prm& p, int id, int t, const float* h_t,
                                               float* h_nx, float* z_t, float* Ls, float* red) {
    int tid = threadIdx.x;
    int lane = tid & 63, wv = tid >> 6;
    int a = id / 16;
    int r = id % 16;
    int b0 = (r & 1) * 64;
    int c0 = (r >> 1) * 32;
    int n0u = __builtin_amdgcn_readfirstlane(c0 + wv * 8);
    const float* heads_a = p.heads + a * SA;
    {
        int rl = tid & 63, zg = tid >> 6;
        int rg = b0 + rl;
        float part = 0.f;
#pragma unroll 4
        for (int i = 0; i < 16; ++i) {
            int zc = zg * 16 + i;
            float em = heads_a[zc * NB + rg];
            float esr = heads_a[(64 + zc) * NB + rg];
            float es = sp(esr);
            float e = p.eps[((size_t)(t * NA + a) * NB + rg) * ZDIM + zc];
            float zv = em + e * es;
            Ls[zc * 64 + rl] = zv;
            if (c0 == 0) z_t[a * ZA + zc * NB + rg] = zv;
            if (c0 == 32) {
                float pm = heads_a[(128 + zc) * NB + rg];
                float ps = sp(heads_a[(192 + zc) * NB + rg]);
                float dm = em - pm;
                part += 0.5f * (2.f * logf(ps) - 2.f * logf(es) +
                                (es * es + dm * dm) / (ps * ps) - 1.f);
            }
        }
        if (c0 == 32) red[tid] = part;
    }
    __syncthreads();
    if (c0 == 32) {
#pragma unroll
        for (int s = 128; s > 0; s >>= 1) {
            if (tid < s) red[tid] += red[tid + s];
            __syncthreads();
        }
        if (tid == 0) atomicAdd(&p.accd[1], (double)red[0]);
        __syncthreads();
    }
    float acc[3][8] = {};
    const float* wp = p.gWih + a * GRU_WIH_S + 2 * 768 + n0u;
#pragma unroll 8
    for (int k = 0; k < 64; ++k) {
        float xv = Ls[k * 64 + lane];
        const float* wr = wp + k * 768;
#pragma unroll
        for (int j = 0; j < 8; ++j) acc[0][j] = fmaf(xv, wr[j], acc[0][j]);
#pragma unroll
        for (int j = 0; j < 8; ++j) acc[1][j] = fmaf(xv, wr[256 + j], acc[1][j]);
#pragma unroll
        for (int j = 0; j < 8; ++j) acc[2][j] = fmaf(xv, wr[512 + j], acc[2][j]);
    }
    int row = b0 + lane;
    float xv0 = p.data[(t + 1) * (NB * YDIM) + row * YDIM + a * XDIM];
    float xv1 = p.data[(t + 1) * (NB * YDIM) + row * YDIM + a * XDIM + 1];
    const float* Wih0 = p.gWih + a * GRU_WIH_S;
    const float* bih = p.gbih + a * 768;
    const float* ghb = p.ghB + a * GA + row;
    const float* hb = h_t + a * SA + row;
    float* ob = h_nx + a * SA + row;
#pragma unroll
    for (int j = 0; j < 8; ++j) {
        int cr = n0u + j;
        float gi0 = acc[0][j] + bih[cr] + xv0 * Wih0[cr] + xv1 * Wih0[768 + cr];
        float gi1 = acc[1][j] + bih[256 + cr] + xv0 * Wih0[256 + cr] + xv1 * Wih0[768 + 256 + cr];
        float gi2 = acc[2][j] + bih[512 + cr] + xv0 * Wih0[512 + cr] + xv1 * Wih0[768 + 512 + cr];
        float hrv = ghb[cr * NB];
        float hzv = ghb[(256 + cr) * NB];
        float hnv = ghb[(512 + cr) * NB];
        float hov = hb[cr * NB];
        float rr = sigm(gi0 + hrv);
        float uu = sigm(gi1 + hzv);
        float nn = tanhf(gi2 + rr * hnv);
        ob[cr * NB] = (1.f - uu) * nn + uu * hov;
    }
    __syncthreads();  // Ls reused by next task / next phase
}

__global__ __launch_bounds__(256, 4) void kmain(Prm p) {
    cg::grid_group grid = cg::this_grid();
    const int tid = threadIdx.x, bid = blockIdx.x;
    const int nb = gridDim.x;
    __shared__ float Ls[64 * 64];
    __shared__ float red[256];
    {
        int g0 = bid * 256 + tid;
        float4* h0 = (float4*)p.h_ring;
        for (int i = g0; i < (NA * SA) / 4; i += nb * 256)
            h0[i] = make_float4(0.f, 0.f, 0.f, 0.f);
        if (g0 == 0) { p.accd[0] = 0.0; p.accd[1] = 0.0; }
    }
    grid.sync();
    for (int t = 0; t <= NSTEP + 8; ++t) {
        const float* h_t = p.h_ring + (size_t)(t % HR) * NA * SA;
        float* h_nx = p.h_ring + (size_t)((t + 1) % HR) * NA * SA;
        float* z_t = p.z_ring + (size_t)(t % TS) * NA * ZA;
        int tD = t - 8, tE = t - 9;
        int nScan = (t < NSTEP) ? 800 : 0;
        int nD1 = (tD >= 0 && tD < NSTEP) ? 160 : 0;
        int nEpi = (tE >= 0 && tE < NSTEP) ? 20 : 0;
        // ---- P1 ----
        for (int id = bid; id < nScan + nD1 + nEpi; id += nb) {
            if (id < nScan) task_l1(p, id, t, h_t);
            else if (id < nScan + nD1) task_dec1(p, id - nScan, tD);
            else task_epi(p, id - nScan - nD1, tE, Ls);
        }
        grid.sync();
        // ---- P2 ----
        int nL2 = (t < NSTEP) ? 320 : 0;
        int nD2 = nD1;
        for (int id = bid; id < nL2 + nD2; id += nb) {
            if (id < nL2) task_l2(p, id);
            else task_dec2(p, id - nL2);
        }
        grid.sync();
        if (t < NSTEP) {
            // ---- P3 ----
            for (int id = bid; id < 160; id += nb) task_heads(p, id);
            grid.sync();
            // ---- P4 ----
            for (int id = bid; id < 160; id += nb)
                task_p4(p, id, t, h_t, h_nx, z_t, Ls, red);
            grid.sync();
        }
    }
    if (bid == 0 && tid == 0) {
        p.out[0] = (float)p.accd[0];
        p.out[1] = (float)p.accd[1];
    }
}

extern "C" void kernel_launch(void* const* d_in, const int* in_sizes, int n_in, void* d_out,
                              int out_size, void* d_ws, size_t ws_size, hipStream_t stream) {
    Prm p;
    p.data = (const float*)d_in[0];
    p.macro = (const int*)d_in[1];
    p.eps = (const float*)d_in[2];
    p.enc_W1 = (const float*)d_in[3];
    p.enc_b1 = (const float*)d_in[4];
    p.enc_W2 = (const float*)d_in[5];
    p.enc_b2 = (const float*)d_in[6];
    p.encm_W = (const float*)d_in[7];
    p.encm_b = (const float*)d_in[8];
    p.encs_W = (const float*)d_in[9];
    p.encs_b = (const float*)d_in[10];
    p.pri_W1 = (const float*)d_in[11];
    p.pri_b1 = (const float*)d_in[12];
    p.pri_W2 = (const float*)d_in[13];
    p.pri_b2 = (const float*)d_in[14];
    p.prim_W = (const float*)d_in[15];
    p.prim_b = (const float*)d_in[16];
    p.pris_W = (const float*)d_in[17];
    p.pris_b = (const float*)d_in[18];
    p.dec_W1 = (const float*)d_in[19];
    p.dec_b1 = (const float*)d_in[20];
    p.dec_W2 = (const float*)d_in[21];
    p.dec_b2 = (const float*)d_in[22];
    p.decm_W = (const float*)d_in[23];
    p.decm_b = (const float*)d_in[24];
    p.decs_W = (const float*)d_in[25];
    p.decs_b = (const float*)d_in[26];
    p.gWih = (const float*)d_in[27];
    p.gbih = (const float*)d_in[28];
    p.gWhh = (const float*)d_in[29];
    p.gbhh = (const float*)d_in[30];

    p.accd = (double*)d_ws;
    float* base = (float*)((char*)d_ws + 256);
    p.h_ring = base;
    p.z_ring = p.h_ring + (size_t)HR * NA * SA;
    p.e1 = p.z_ring + (size_t)TS * NA * ZA;
    p.p1 = p.e1 + NA * SA;
    p.e2 = p.p1 + NA * SA;
    p.p2 = p.e2 + NA * SA;
    p.heads = p.p2 + NA * SA;
    p.ghB = p.heads + NA * SA;
    p.dech1 = p.ghB + (size_t)NA * GA;
    p.dech2 = p.dech1 + NA * SA;
    p.out = (float*)d_out;

    int bpc = 0;
    hipOccupancyMaxActiveBlocksPerMultiprocessor(&bpc, (const void*)kmain, 256, 0);
    if (bpc < 1) bpc = 1;
    int grid = bpc * 256;
    if (grid > MAXTASK) grid = MAXTASK;

    void* args[] = {&p};
    hipLaunchCooperativeKernel((void*)kmain, dim3(grid), dim3(256), args, 0, stream);
}

// Round 7
// 34797.055 us; speedup vs baseline: 1.1423x; 1.1423x over previous
//
#include <hip/hip_runtime.h>
#include <hip/hip_cooperative_groups.h>
#include <math.h>

namespace cg = cooperative_groups;

#define NA 10
#define NB 128
#define XDIM 2
#define YDIM 20
#define ZDIM 64
#define HDIM 256
#define NSTEP 64
#define TS 8
#define HR (TS + 1)
#define MAXGRID 512
#define LOG2PI 1.8378770664093453f

#define ENC_W1_S (348 * 256)
#define PRI_W1_S (346 * 256)
#define DEC_W1_S (430 * 256)
#define GRU_WIH_S (66 * 768)
#define GRU_WHH_S (256 * 768)
#define W2_S (256 * 256)
#define HEADW_S (256 * 64)

// col-major activation panels: [C][NB] per agent
#define SA (256 * NB)
#define GA (768 * NB)
#define ZA (ZDIM * NB)

static __device__ __forceinline__ float sp(float x) {
    return fmaxf(x, 0.f) + log1pf(expf(-fabsf(x)));
}
static __device__ __forceinline__ float sigm(float x) { return 1.f / (1.f + expf(-x)); }
static __device__ __forceinline__ float relu(float x) { return fmaxf(x, 0.f); }

struct Prm {
    const float* data;
    const int* macro;
    const float* eps;
    const float *enc_W1, *enc_b1, *enc_W2, *enc_b2, *encm_W, *encm_b, *encs_W, *encs_b;
    const float *pri_W1, *pri_b1, *pri_W2, *pri_b2, *prim_W, *prim_b, *pris_W, *pris_b;
    const float *dec_W1, *dec_b1, *dec_W2, *dec_b2, *decm_W, *decm_b, *decs_W, *decs_b;
    const float *gWih, *gbih, *gWhh, *gbhh;
    float *h_ring, *z_ring, *e1, *p1, *e2, *p2, *heads, *ghB, *dech1, *dech2;
    float* dataT;  // [NT][YDIM][NB] col-major per (t,c)
    int* macroT;   // [NT][NA][NB]
    double* accd;
    float* out;
};

// K-loop core: acc[i] += X[k][r0+i] * W[k][col].  Xu: wave-uniform base (X col-major,
// row-chunk start). Wl: per-lane column pointer (coalesced vector loads).
static __device__ __forceinline__ void gemv16(float acc[16], const float* __restrict__ Xu,
                                              const float* __restrict__ Wl, int wld, int K) {
#pragma unroll 4
    for (int k = 0; k < K; ++k) {
        float w = Wl[k * wld];
        const float* xk = Xu + k * NB;
#pragma unroll
        for (int i = 0; i < 16; ++i) acc[i] = fmaf(xk[i], w, acc[i]);
    }
}

// ---- enc1 / pri1: q in 0..79: a=q/8, ct=(q%8)>>1, rt=q&1 ----
static __device__ __forceinline__ void task_ep1(const Prm& p, int q, int ep, int t,
                                                const float* h_t) {
    int tid = threadIdx.x, lane = tid & 63, wv = tid >> 6;
    int a = q >> 3;
    int e = q & 7;
    int ct = e >> 1, rt = e & 1;
    int col = ct * 64 + lane;
    int r0 = __builtin_amdgcn_readfirstlane(rt * 64 + wv * 16);
    const float* W1b = ep ? p.pri_W1 + a * PRI_W1_S : p.enc_W1 + a * ENC_W1_S;
    const float* Wb = W1b + (ep ? 90 : 92) * 256;
    const float* Xu = h_t + a * SA + r0;
    float acc[16] = {};
    gemv16(acc, Xu, Wb + col, 256, 256);
    const float* bbp = ep ? p.pri_b1 + a * HDIM : p.enc_b1 + a * HDIM;
    float bias = bbp[col];
    float wx0 = 0.f, wx1 = 0.f;
    if (ep == 0) { wx0 = W1b[col]; wx1 = W1b[256 + col]; }
    const int* mT = p.macroT + (t * NA + a) * NB + r0;
    const float* xT0 = p.dataT + (size_t)((t + 1) * YDIM + a * XDIM) * NB + r0;
    const float* xT1 = xT0 + NB;
    float* ob = (ep ? p.p1 : p.e1) + a * SA + (size_t)col * NB + r0;
#pragma unroll
    for (int i = 0; i < 16; ++i) {
        int mi = mT[i];
        float mv = W1b[(ep ? mi : 2 + mi) * 256 + col];
        float v = acc[i] + bias + mv;
        if (ep == 0) v += xT0[i] * wx0 + xT1[i] * wx1;
        ob[i] = relu(v);
    }
}

// ---- gh: q in 0..239: a=q/24, ct=(q%24)>>1 (0..11), rt=q&1 ----
static __device__ __forceinline__ void task_gh(const Prm& p, int q, const float* h_t) {
    int tid = threadIdx.x, lane = tid & 63, wv = tid >> 6;
    int a = q / 24;
    int e = q % 24;
    int ct = e >> 1, rt = e & 1;
    int col = ct * 64 + lane;
    int r0 = __builtin_amdgcn_readfirstlane(rt * 64 + wv * 16);
    const float* Xu = h_t + a * SA + r0;
    float acc[16] = {};
    gemv16(acc, Xu, p.gWhh + a * GRU_WHH_S + col, 768, 256);
    float bias = p.gbhh[a * 768 + col];
    float* ob = p.ghB + a * GA + (size_t)col * NB + r0;
#pragma unroll
    for (int i = 0; i < 16; ++i) ob[i] = acc[i] + bias;
}

// ---- generic 256->256 layer (enc2/pri2/dec2): q in 0..79 ----
static __device__ __forceinline__ void task_l2(const Prm& p, int q, const float* Xpanel,
                                               const float* Wbase, const float* bias,
                                               float* outp) {
    int tid = threadIdx.x, lane = tid & 63, wv = tid >> 6;
    int a = q >> 3;
    int e = q & 7;
    int ct = e >> 1, rt = e & 1;
    int col = ct * 64 + lane;
    int r0 = __builtin_amdgcn_readfirstlane(rt * 64 + wv * 16);
    const float* Xu = Xpanel + a * SA + r0;
    float acc[16] = {};
    gemv16(acc, Xu, Wbase + a * W2_S + col, 256, 256);
    float bb = bias[a * HDIM + col];
    float* ob = outp + a * SA + (size_t)col * NB + r0;
#pragma unroll
    for (int i = 0; i < 16; ++i) ob[i] = relu(acc[i] + bb);
}

// ---- heads: q in 0..79: a=q/8, head=(q%8)>>1, rt=q&1 ----
static __device__ __forceinline__ void task_heads(const Prm& p, int q) {
    int tid = threadIdx.x, lane = tid & 63, wv = tid >> 6;
    int a = q >> 3;
    int e = q & 7;
    int head = e >> 1, rt = e & 1;
    int r0 = __builtin_amdgcn_readfirstlane(rt * 64 + wv * 16);
    const float* Wt;
    const float* Bt;
    if (head == 0) { Wt = p.encm_W; Bt = p.encm_b; }
    else if (head == 1) { Wt = p.encs_W; Bt = p.encs_b; }
    else if (head == 2) { Wt = p.prim_W; Bt = p.prim_b; }
    else { Wt = p.pris_W; Bt = p.pris_b; }
    const float* Xu = (head < 2 ? p.e2 : p.p2) + a * SA + r0;
    float acc[16] = {};
    gemv16(acc, Xu, Wt + a * HEADW_S + lane, 64, 256);
    float bb = Bt[a * ZDIM + lane];
    float* ob = p.heads + a * SA + (size_t)(head * 64 + lane) * NB + r0;
#pragma unroll
    for (int i = 0; i < 16; ++i) ob[i] = acc[i] + bb;
}

// ---- dec1 [tD]: q in 0..79 ----
static __device__ __forceinline__ void task_dec1(const Prm& p, int q, int tD) {
    int tid = threadIdx.x, lane = tid & 63, wv = tid >> 6;
    int a = q >> 3;
    int e = q & 7;
    int ct = e >> 1, rt = e & 1;
    int col = ct * 64 + lane;
    int r0 = __builtin_amdgcn_readfirstlane(rt * 64 + wv * 16);
    const float* Wb = p.dec_W1 + a * DEC_W1_S;
    const float* Wl = Wb + col;
    float acc[16] = {};
    // y segment (W rows 0..19)
    gemv16(acc, p.dataT + (size_t)(tD * YDIM) * NB + r0, Wl, 256, 20);
    // z segment (W rows 110..173)
    gemv16(acc, p.z_ring + (size_t)(tD % TS) * (NA * ZA) + a * ZA + r0, Wl + 110 * 256, 256, 64);
    // h segment (W rows 174..429)
    gemv16(acc, p.h_ring + (size_t)(tD % HR) * (NA * SA) + a * SA + r0, Wl + 174 * 256, 256, 256);
    float bias = p.dec_b1[a * HDIM + col];
    const int* mT = p.macroT + (tD * NA + a) * NB + r0;
    float* ob = p.dech1 + a * SA + (size_t)col * NB + r0;
#pragma unroll
    for (int i = 0; i < 16; ++i) {
        int mi = mT[i];
        float mv = Wb[(20 + mi) * 256 + col];
        ob[i] = relu(acc[i] + bias + mv);
    }
}

// ---- recon epilogue [tE]: q in 0..19 (lane=row mapping), uses Lsh(16x64) ----
static __device__ __forceinline__ void task_epi(const Prm& p, int q, int tE, float* Ls) {
    int tid = threadIdx.x, lane = tid & 63, wv = tid >> 6;
    int a = q >> 1;
    int b0 = (q & 1) * 64;
    int row = b0 + lane;
    const float* d2 = p.dech2 + a * SA;
    const float* wm = p.decm_W + a * (HDIM * XDIM);
    const float* ws = p.decs_W + a * (HDIM * XDIM);
    float m0 = 0.f, m1 = 0.f, s0 = 0.f, s1 = 0.f;
#pragma unroll 8
    for (int kk = 0; kk < 64; ++kk) {
        int k = wv * 64 + kk;
        float xv = d2[k * NB + row];
        m0 = fmaf(xv, wm[k * 2], m0);
        m1 = fmaf(xv, wm[k * 2 + 1], m1);
        s0 = fmaf(xv, ws[k * 2], s0);
        s1 = fmaf(xv, ws[k * 2 + 1], s1);
    }
    Ls[(wv * 4 + 0) * 64 + lane] = m0;
    Ls[(wv * 4 + 1) * 64 + lane] = m1;
    Ls[(wv * 4 + 2) * 64 + lane] = s0;
    Ls[(wv * 4 + 3) * 64 + lane] = s1;
    __syncthreads();
    if (wv == 0) {
        float M0 = Ls[0 * 64 + lane] + Ls[4 * 64 + lane] + Ls[8 * 64 + lane] + Ls[12 * 64 + lane];
        float M1 = Ls[1 * 64 + lane] + Ls[5 * 64 + lane] + Ls[9 * 64 + lane] + Ls[13 * 64 + lane];
        float S0 = Ls[2 * 64 + lane] + Ls[6 * 64 + lane] + Ls[10 * 64 + lane] + Ls[14 * 64 + lane];
        float S1 = Ls[3 * 64 + lane] + Ls[7 * 64 + lane] + Ls[11 * 64 + lane] + Ls[15 * 64 + lane];
        float dm0 = M0 + p.decm_b[a * 2 + 0];
        float dm1 = M1 + p.decm_b[a * 2 + 1];
        float ds0 = sp(S0 + p.decs_b[a * 2 + 0]);
        float ds1 = sp(S1 + p.decs_b[a * 2 + 1]);
        int targ = tE + 1;
        float x0 = p.data[targ * (NB * YDIM) + row * YDIM + a * XDIM + 0];
        float x1 = p.data[targ * (NB * YDIM) + row * YDIM + a * XDIM + 1];
        float r0 = (x0 - dm0) / ds0, r1 = (x1 - dm1) / ds1;
        float tt = 0.5f * r0 * r0 + logf(ds0) + 0.5f * LOG2PI + 0.5f * r1 * r1 + logf(ds1) +
                   0.5f * LOG2PI;
#pragma unroll
        for (int off = 32; off > 0; off >>= 1) tt += __shfl_down(tt, off, 64);
        if (lane == 0) atomicAdd(&p.accd[0], (double)tt);
    }
    __syncthreads();
}

// ---- P4: z-prep (LDS) + KL (ct==0) + gi(3 gates) + GRU combine. q in 0..79 ----
static __device__ __forceinline__ void task_gi(const Prm& p, int q, int t, const float* h_t,
                                               float* h_nx, float* z_t, float* Lz, float* red) {
    int tid = threadIdx.x, lane = tid & 63, wv = tid >> 6;
    int a = q >> 3;
    int e = q & 7;
    int ct = e >> 1, rt = e & 1;
    int r0b = __builtin_amdgcn_readfirstlane(rt * 64);
    // --- z-prep: thread handles zc = tid>>2, rows rch..rch+15 ---
    {
        int zc = tid >> 2, rch = (tid & 3) * 16;
        const float* emp = p.heads + a * SA + (size_t)zc * NB + r0b + rch;
        const float* esp = emp + (size_t)64 * NB;
        const float* ep_ = p.eps + ((size_t)(t * NA + a) * NB + r0b + rch) * ZDIM + zc;
        float* Ld = Lz + zc * 64 + rch;
        if (ct == 0) {
            const float* pmp = emp + (size_t)128 * NB;
            const float* psp = emp + (size_t)192 * NB;
            float* zo = z_t + a * ZA + (size_t)zc * NB + r0b + rch;
            float kl = 0.f;
#pragma unroll 4
            for (int i = 0; i < 16; ++i) {
                float em = emp[i];
                float es = sp(esp[i]);
                float zv = em + ep_[i * ZDIM] * es;
                Ld[i] = zv;
                zo[i] = zv;
                float pm = pmp[i];
                float ps = sp(psp[i]);
                float dm = em - pm;
                kl += 0.5f * (2.f * logf(ps) - 2.f * logf(es) +
                              (es * es + dm * dm) / (ps * ps) - 1.f);
            }
            red[tid] = kl;
        } else {
#pragma unroll 4
            for (int i = 0; i < 16; ++i) {
                float em = emp[i];
                float es = sp(esp[i]);
                Ld[i] = em + ep_[i * ZDIM] * es;
            }
        }
    }
    __syncthreads();
    if (ct == 0) {
#pragma unroll
        for (int s = 128; s > 0; s >>= 1) {
            if (tid < s) red[tid] += red[tid + s];
            __syncthreads();
        }
        if (tid == 0) atomicAdd(&p.accd[1], (double)red[0]);
    }
    // --- gi: 3 gates for h-cols ct*64+lane, rows r0b + wv*16 .. +16 ---
    int col = ct * 64 + lane;
    int r0l = __builtin_amdgcn_readfirstlane(wv * 16);
    const float* Wl = p.gWih + a * GRU_WIH_S + 2 * 768 + col;
    float a0[16] = {}, a1[16] = {}, a2[16] = {};
#pragma unroll 2
    for (int k = 0; k < ZDIM; ++k) {
        float w0 = Wl[k * 768];
        float w1 = Wl[k * 768 + 256];
        float w2 = Wl[k * 768 + 512];
        const float* xz = Lz + k * 64 + r0l;
#pragma unroll
        for (int i = 0; i < 16; ++i) {
            float x = xz[i];
            a0[i] = fmaf(x, w0, a0[i]);
            a1[i] = fmaf(x, w1, a1[i]);
            a2[i] = fmaf(x, w2, a2[i]);
        }
    }
    // --- combine ---
    int r0 = r0b + r0l;
    const float* Wih0 = p.gWih + a * GRU_WIH_S;
    const float* bih = p.gbih + a * 768;
    float b0v = bih[col], b1v = bih[256 + col], b2v = bih[512 + col];
    float wx00 = Wih0[col], wx01 = Wih0[768 + col];
    float wx10 = Wih0[256 + col], wx11 = Wih0[768 + 256 + col];
    float wx20 = Wih0[512 + col], wx21 = Wih0[768 + 512 + col];
    const float* xT0 = p.dataT + (size_t)((t + 1) * YDIM + a * XDIM) * NB + r0;
    const float* xT1 = xT0 + NB;
    const float* ghr = p.ghB + a * GA + (size_t)col * NB + r0;
    const float* ghz = ghr + (size_t)256 * NB;
    const float* ghn = ghr + (size_t)512 * NB;
    const float* hb = h_t + a * SA + (size_t)col * NB + r0;
    float* ob = h_nx + a * SA + (size_t)col * NB + r0;
#pragma unroll
    for (int i = 0; i < 16; ++i) {
        float gi0 = a0[i] + b0v + xT0[i] * wx00 + xT1[i] * wx01;
        float gi1 = a1[i] + b1v + xT0[i] * wx10 + xT1[i] * wx11;
        float gi2 = a2[i] + b2v + xT0[i] * wx20 + xT1[i] * wx21;
        float rr = sigm(gi0 + ghr[i]);
        float uu = sigm(gi1 + ghz[i]);
        float nn = tanhf(gi2 + rr * ghn[i]);
        ob[i] = (1.f - uu) * nn + uu * hb[i];
    }
    __syncthreads();
}

__global__ __launch_bounds__(256, 2) void kmain(Prm p) {
    cg::grid_group grid = cg::this_grid();
    const int tid = threadIdx.x, bid = blockIdx.x;
    const int nb = gridDim.x;
    __shared__ float Lsh[4096];  // 16 KB: Lz for gi, Ls for epi
    __shared__ float red[256];
    // ---- init: zero h0/accd, build dataT + macroT ----
    {
        int g0 = bid * 256 + tid;
        int nthr = nb * 256;
        float4* h0 = (float4*)p.h_ring;
        for (int i = g0; i < (NA * SA) / 4; i += nthr) h0[i] = make_float4(0.f, 0.f, 0.f, 0.f);
        for (int i = g0; i < 65 * YDIM * NB; i += nthr) {
            int r = i & 127;
            int c = (i >> 7) % YDIM;
            int t = i / (YDIM * NB);
            p.dataT[i] = p.data[(t * NB + r) * YDIM + c];
        }
        for (int i = g0; i < 65 * NA * NB; i += nthr) {
            int r = i & 127;
            int a = (i >> 7) % NA;
            int t = i / (NA * NB);
            p.macroT[i] = p.macro[(t * NB + r) * NA + a];
        }
        if (g0 == 0) { p.accd[0] = 0.0; p.accd[1] = 0.0; }
    }
    grid.sync();
    for (int t = 0; t <= NSTEP + 8; ++t) {
        const float* h_t = p.h_ring + (size_t)(t % HR) * NA * SA;
        float* h_nx = p.h_ring + (size_t)((t + 1) % HR) * NA * SA;
        float* z_t = p.z_ring + (size_t)(t % TS) * NA * ZA;
        bool scan = t < NSTEP;
        int tD = t - 8, tE = t - 9;
        bool d1 = (tD >= 0 && tD < NSTEP);
        bool epA = (tE >= 0 && tE < NSTEP);
        int nEnc = scan ? 80 : 0, nPri = scan ? 80 : 0, nGh = scan ? 240 : 0;
        int nD1 = d1 ? 80 : 0, nEp = epA ? 20 : 0;
        // ---- P1: enc1 + pri1 + gh + dec1[tD] + epi[tE] ----
        int tot1 = nEnc + nPri + nGh + nD1 + nEp;
        for (int id = bid; id < tot1; id += nb) {
            int x = id;
            if (x < nEnc) task_ep1(p, x, 0, t, h_t);
            else if ((x -= nEnc) < nPri) task_ep1(p, x, 1, t, h_t);
            else if ((x -= nPri) < nGh) task_gh(p, x, h_t);
            else if ((x -= nGh) < nD1) task_dec1(p, x, tD);
            else task_epi(p, x - nD1, tE, Lsh);
        }
        grid.sync();
        // ---- P2: enc2 + pri2 + dec2 ----
        int nL = scan ? 80 : 0;
        int tot2 = 2 * nL + nD1;
        for (int id = bid; id < tot2; id += nb) {
            int x = id;
            if (x < nL) task_l2(p, x, p.e1, p.enc_W2, p.enc_b2, p.e2);
            else if ((x -= nL) < nL) task_l2(p, x, p.p1, p.pri_W2, p.pri_b2, p.p2);
            else task_l2(p, x - nL, p.dech1, p.dec_W2, p.dec_b2, p.dech2);
        }
        grid.sync();
        if (scan) {
            // ---- P3: heads ----
            for (int id = bid; id < 80; id += nb) task_heads(p, id);
            grid.sync();
            // ---- P4: z + KL + gi + combine ----
            for (int id = bid; id < 80; id += nb)
                task_gi(p, id, t, h_t, h_nx, z_t, Lsh, red);
            grid.sync();
        }
    }
    if (bid == 0 && tid == 0) {
        p.out[0] = (float)p.accd[0];
        p.out[1] = (float)p.accd[1];
    }
}

extern "C" void kernel_launch(void* const* d_in, const int* in_sizes, int n_in, void* d_out,
                              int out_size, void* d_ws, size_t ws_size, hipStream_t stream) {
    Prm p;
    p.data = (const float*)d_in[0];
    p.macro = (const int*)d_in[1];
    p.eps = (const float*)d_in[2];
    p.enc_W1 = (const float*)d_in[3];
    p.enc_b1 = (const float*)d_in[4];
    p.enc_W2 = (const float*)d_in[5];
    p.enc_b2 = (const float*)d_in[6];
    p.encm_W = (const float*)d_in[7];
    p.encm_b = (const float*)d_in[8];
    p.encs_W = (const float*)d_in[9];
    p.encs_b = (const float*)d_in[10];
    p.pri_W1 = (const float*)d_in[11];
    p.pri_b1 = (const float*)d_in[12];
    p.pri_W2 = (const float*)d_in[13];
    p.pri_b2 = (const float*)d_in[14];
    p.prim_W = (const float*)d_in[15];
    p.prim_b = (const float*)d_in[16];
    p.pris_W = (const float*)d_in[17];
    p.pris_b = (const float*)d_in[18];
    p.dec_W1 = (const float*)d_in[19];
    p.dec_b1 = (const float*)d_in[20];
    p.dec_W2 = (const float*)d_in[21];
    p.dec_b2 = (const float*)d_in[22];
    p.decm_W = (const float*)d_in[23];
    p.decm_b = (const float*)d_in[24];
    p.decs_W = (const float*)d_in[25];
    p.decs_b = (const float*)d_in[26];
    p.gWih = (const float*)d_in[27];
    p.gbih = (const float*)d_in[28];
    p.gWhh = (const float*)d_in[29];
    p.gbhh = (const float*)d_in[30];

    p.accd = (double*)d_ws;
    float* base = (float*)((char*)d_ws + 256);
    p.h_ring = base;                                // HR*NA*SA
    p.z_ring = p.h_ring + (size_t)HR * NA * SA;     // TS*NA*ZA
    p.e1 = p.z_ring + (size_t)TS * NA * ZA;
    p.p1 = p.e1 + NA * SA;
    p.e2 = p.p1 + NA * SA;
    p.p2 = p.e2 + NA * SA;
    p.heads = p.p2 + NA * SA;
    p.ghB = p.heads + NA * SA;                      // NA*GA
    p.dech1 = p.ghB + (size_t)NA * GA;
    p.dech2 = p.dech1 + NA * SA;
    p.dataT = p.dech2 + NA * SA;                    // 65*20*128
    p.macroT = (int*)(p.dataT + 65 * YDIM * NB);    // 65*10*128
    p.out = (float*)d_out;

    int bpc = 0;
    hipOccupancyMaxActiveBlocksPerMultiprocessor(&bpc, (const void*)kmain, 256, 0);
    if (bpc < 1) bpc = 1;
    int grid = bpc * 256;
    if (grid > MAXGRID) grid = MAXGRID;

    void* args[] = {&p};
    hipLaunchCooperativeKernel((void*)kmain, dim3(grid), dim3(256), args, 0, stream);
}

// Round 10
// 16136.214 us; speedup vs baseline: 2.4633x; 2.1565x over previous
//
#include <hip/hip_runtime.h>
#include <math.h>

#define NA 10
#define NB 128
#define YD 20
#define ZD 64
#define HD 256
#define NSTEP 64
#define LOG2PI 1.8378770664093453f

#define ENC_W1_S (348 * 256)
#define PRI_W1_S (346 * 256)
#define DEC_W1_S (430 * 256)
#define GWIH_S (66 * 768)
#define GWHH_S (256 * 768)
#define W2_S (256 * 256)
#define HW_S (256 * 64)

static __device__ __forceinline__ float sp(float x) {
    return fmaxf(x, 0.f) + log1pf(expf(-fabsf(x)));
}
static __device__ __forceinline__ float sigm(float x) { return 1.f / (1.f + expf(-x)); }
static __device__ __forceinline__ float relu(float x) { return fmaxf(x, 0.f); }

struct Prm {
    const float* data;
    const int* macro;
    const float* eps;
    const float *enc_W1, *enc_b1, *enc_W2, *enc_b2, *encm_W, *encm_b, *encs_W, *encs_b;
    const float *pri_W1, *pri_b1, *pri_W2, *pri_b2, *prim_W, *prim_b, *pris_W, *pris_b;
    const float *dec_W1, *dec_b1, *dec_W2, *dec_b2, *decm_W, *decm_b, *decs_W, *decs_b;
    const float *gWih, *gbih, *gWhh, *gbhh;
    double* accd;
};

// acc[r] += sum_k X[r*XS+k] * Wc[k*wld], k ascending. X: LDS (wave-broadcast reads).
// Wc: per-lane column pointer -> each k is one coalesced 256B wave load.
static __device__ __forceinline__ void gemv4(float acc[4], const float* X, int XS, int K,
                                             const float* __restrict__ Wc, int wld) {
#pragma unroll 2
    for (int k4 = 0; k4 < K; k4 += 4) {
        float w0 = Wc[(k4 + 0) * wld];
        float w1 = Wc[(k4 + 1) * wld];
        float w2 = Wc[(k4 + 2) * wld];
        float w3 = Wc[(k4 + 3) * wld];
#pragma unroll
        for (int r = 0; r < 4; ++r) {
            float4 x = *(const float4*)&X[r * XS + k4];
            acc[r] = fmaf(x.x, w0, acc[r]);
            acc[r] = fmaf(x.y, w1, acc[r]);
            acc[r] = fmaf(x.z, w2, acc[r]);
            acc[r] = fmaf(x.w, w3, acc[r]);
        }
    }
}

__global__ void kzero(double* accd) {
    if (threadIdx.x == 0) {
        accd[0] = 0.0;
        accd[1] = 0.0;
    }
}

__global__ void kfinal(const double* __restrict__ accd, float* __restrict__ out) {
    if (threadIdx.x == 0) {
        out[0] = (float)accd[0];
        out[1] = (float)accd[1];
    }
}

// 160 blocks x 512 threads. block = (agent a, 8-row tile) via XCD-aware swizzle.
// Wave w: rsel=w>>2 (row half: rows rsel*4..+3), wgrp=w&3 (cols wgrp*64..+63).
// Whole 64-step scan in-block; h + activations in LDS; weights stream from L2/L3.
__global__ __launch_bounds__(512) void kmain(Prm p) {
    __shared__ float H[8 * 256];
    __shared__ float Pa[8 * 256];
    __shared__ float Pb[8 * 256];
    __shared__ float Pc[8 * 256];
    __shared__ float D[8 * 256];
    __shared__ float Zp[8 * 64];
    __shared__ float red[512];
    __shared__ double bAcc[2];

    const int tid = threadIdx.x;
    const int w = tid >> 6, l = tid & 63;
    const int rsel = w >> 2, wgrp = w & 3;
    const int r0 = rsel * 4;
    const int c = wgrp * 64 + l;
    // XCD swizzle: dispatch round-robins bid%8 -> XCD; make each XCD host ~2 agents.
    const int jid = (blockIdx.x & 7) * 20 + (blockIdx.x >> 3);
    const int a = jid >> 4;
    const int row0 = (jid & 15) * 8;

    const float* eW1 = p.enc_W1 + a * ENC_W1_S;
    const float* pW1 = p.pri_W1 + a * PRI_W1_S;
    const float* dW1 = p.dec_W1 + a * DEC_W1_S;
    const float* eW2 = p.enc_W2 + a * W2_S;
    const float* pW2 = p.pri_W2 + a * W2_S;
    const float* dW2 = p.dec_W2 + a * W2_S;
    const float* Whh = p.gWhh + a * GWHH_S;
    const float* Wih = p.gWih + a * GWIH_S;

#pragma unroll
    for (int r = 0; r < 4; ++r) H[(r0 + r) * 256 + c] = 0.f;
    if (tid == 0) {
        bAcc[0] = 0.0;
        bAcc[1] = 0.0;
    }
    __syncthreads();

    for (int t = 0; t < NSTEP; ++t) {
        // ---- S0: enc1 (H -> Pa) ----
        {
            float acc[4] = {};
            gemv4(acc, H + r0 * 256, 256, 256, eW1 + 92 * 256 + c, 256);
            float be = p.enc_b1[a * HD + c];
            float wx0 = eW1[c], wx1 = eW1[256 + c];
#pragma unroll
            for (int r = 0; r < 4; ++r) {
                int row = row0 + r0 + r;
                int mi = p.macro[(t * NB + row) * NA + a];
                float x0 = p.data[(t + 1) * (NB * YD) + row * YD + a * 2];
                float x1 = p.data[(t + 1) * (NB * YD) + row * YD + a * 2 + 1];
                float v = acc[r] + be + eW1[(2 + mi) * 256 + c] + x0 * wx0 + x1 * wx1;
                Pa[(r0 + r) * 256 + c] = relu(v);
            }
        }
        __syncthreads();
        // ---- S1: enc2 (Pa -> Pb) ----
        {
            float acc[4] = {};
            gemv4(acc, Pa + r0 * 256, 256, 256, eW2 + c, 256);
            float bb = p.enc_b2[a * HD + c];
#pragma unroll
            for (int r = 0; r < 4; ++r) Pb[(r0 + r) * 256 + c] = relu(acc[r] + bb);
        }
        __syncthreads();
        // ---- S2: enc heads (Pb -> Pa[0..127]); col-groups 0,1 ----
        if (wgrp < 2) {
            const float* Wh = (wgrp == 0 ? p.encm_W : p.encs_W) + a * HW_S + l;
            const float* Bh = (wgrp == 0 ? p.encm_b : p.encs_b) + a * ZD;
            float acc[4] = {};
            gemv4(acc, Pb + r0 * 256, 256, 256, Wh, 64);
            float bb = Bh[l];
#pragma unroll
            for (int r = 0; r < 4; ++r) Pa[(r0 + r) * 256 + wgrp * 64 + l] = acc[r] + bb;
        }
        __syncthreads();
        // ---- S3: pri1 (H -> Pb) ----
        {
            float acc[4] = {};
            gemv4(acc, H + r0 * 256, 256, 256, pW1 + 90 * 256 + c, 256);
            float bp = p.pri_b1[a * HD + c];
#pragma unroll
            for (int r = 0; r < 4; ++r) {
                int row = row0 + r0 + r;
                int mi = p.macro[(t * NB + row) * NA + a];
                Pb[(r0 + r) * 256 + c] = relu(acc[r] + bp + pW1[mi * 256 + c]);
            }
        }
        __syncthreads();
        // ---- S4: pri2 (Pb -> Pc) ----
        {
            float acc[4] = {};
            gemv4(acc, Pb + r0 * 256, 256, 256, pW2 + c, 256);
            float bb = p.pri_b2[a * HD + c];
#pragma unroll
            for (int r = 0; r < 4; ++r) Pc[(r0 + r) * 256 + c] = relu(acc[r] + bb);
        }
        __syncthreads();
        // ---- S5: pri heads (Pc -> Pa[128..255]); col-groups 2,3 ----
        if (wgrp >= 2) {
            const float* Wh = (wgrp == 2 ? p.prim_W : p.pris_W) + a * HW_S + l;
            const float* Bh = (wgrp == 2 ? p.prim_b : p.pris_b) + a * ZD;
            float acc[4] = {};
            gemv4(acc, Pc + r0 * 256, 256, 256, Wh, 64);
            float bb = Bh[l];
#pragma unroll
            for (int r = 0; r < 4; ++r)
                Pa[(r0 + r) * 256 + 128 + (wgrp - 2) * 64 + l] = acc[r] + bb;
        }
        __syncthreads();
        // ---- S6: z + KL (Pa -> Zp, bAcc[1]); thread = (row w, z-col l) ----
        {
            int r = w;
            int row = row0 + r;
            float em = Pa[r * 256 + l];
            float es = sp(Pa[r * 256 + 64 + l]);
            float pm = Pa[r * 256 + 128 + l];
            float ps = sp(Pa[r * 256 + 192 + l]);
            float e = p.eps[((size_t)(t * NA + a) * NB + row) * ZD + l];
            Zp[r * 64 + l] = em + e * es;
            float dm = em - pm;
            red[tid] = 0.5f * (2.f * logf(ps) - 2.f * logf(es) +
                               (es * es + dm * dm) / (ps * ps) - 1.f);
        }
        __syncthreads();
#pragma unroll
        for (int s = 256; s > 0; s >>= 1) {
            if (tid < s) red[tid] += red[tid + s];
            __syncthreads();
        }
        if (tid == 0) bAcc[1] += (double)red[0];
        __syncthreads();
        // ---- stage y_t rows into red[0..159] ----
        if (tid < 160) {
            int r = tid / YD, k = tid - r * YD;
            red[tid] = p.data[t * (NB * YD) + (row0 + r) * YD + k];
        }
        __syncthreads();
        // ---- S7: dec1 (y + Zp + H -> Pb) ----
        {
            float acc[4] = {};
            const float* Wc = dW1 + c;
#pragma unroll 4
            for (int k = 0; k < YD; ++k) {
                float wv = Wc[k * 256];
#pragma unroll
                for (int r = 0; r < 4; ++r) acc[r] = fmaf(red[(r0 + r) * YD + k], wv, acc[r]);
            }
            gemv4(acc, Zp + r0 * 64, 64, 64, Wc + 110 * 256, 256);
            gemv4(acc, H + r0 * 256, 256, 256, Wc + 174 * 256, 256);
            float bd = p.dec_b1[a * HD + c];
#pragma unroll
            for (int r = 0; r < 4; ++r) {
                int row = row0 + r0 + r;
                int mi = p.macro[(t * NB + row) * NA + a];
                Pb[(r0 + r) * 256 + c] = relu(acc[r] + bd + dW1[(20 + mi) * 256 + c]);
            }
        }
        __syncthreads();
        // ---- S8: dec2 (Pb -> Pc) ----
        {
            float acc[4] = {};
            gemv4(acc, Pb + r0 * 256, 256, 256, dW2 + c, 256);
            float bb = p.dec_b2[a * HD + c];
#pragma unroll
            for (int r = 0; r < 4; ++r) Pc[(r0 + r) * 256 + c] = relu(acc[r] + bb);
        }
        __syncthreads();
        // ---- S9: recon (Pc + dec heads -> bAcc[0]); wave w = row w ----
        {
            int r = w;
            int ks = l * 4;
            float m0 = 0.f, m1 = 0.f, s0 = 0.f, s1 = 0.f;
#pragma unroll
            for (int j = 0; j < 4; ++j) {
                int k = ks + j;
                float xv = Pc[r * 256 + k];
                m0 = fmaf(xv, p.decm_W[a * 512 + k * 2], m0);
                m1 = fmaf(xv, p.decm_W[a * 512 + k * 2 + 1], m1);
                s0 = fmaf(xv, p.decs_W[a * 512 + k * 2], s0);
                s1 = fmaf(xv, p.decs_W[a * 512 + k * 2 + 1], s1);
            }
#pragma unroll
            for (int off = 32; off > 0; off >>= 1) {
                m0 += __shfl_down(m0, off, 64);
                m1 += __shfl_down(m1, off, 64);
                s0 += __shfl_down(s0, off, 64);
                s1 += __shfl_down(s1, off, 64);
            }
            if (l == 0) {
                int row = row0 + r;
                float dm0 = m0 + p.decm_b[a * 2];
                float dm1 = m1 + p.decm_b[a * 2 + 1];
                float ds0 = sp(s0 + p.decs_b[a * 2]);
                float ds1 = sp(s1 + p.decs_b[a * 2 + 1]);
                float x0 = p.data[(t + 1) * (NB * YD) + row * YD + a * 2];
                float x1 = p.data[(t + 1) * (NB * YD) + row * YD + a * 2 + 1];
                float q0 = (x0 - dm0) / ds0, q1 = (x1 - dm1) / ds1;
                red[r] = 0.5f * q0 * q0 + logf(ds0) + 0.5f * LOG2PI + 0.5f * q1 * q1 +
                         logf(ds1) + 0.5f * LOG2PI;
            }
        }
        __syncthreads();
        if (tid == 0) {
            float s = 0.f;
#pragma unroll
            for (int r = 0; r < 8; ++r) s += red[r];
            bAcc[0] += (double)s;
        }
        // ---- S10: GRU (H, Zp -> D) ----
        {
            float g0[4], g1[4], g2[4];
            {
                float acc[4] = {};
                gemv4(acc, H + r0 * 256, 256, 256, Whh + c, 768);
                float bb = p.gbhh[a * 768 + c];
#pragma unroll
                for (int r = 0; r < 4; ++r) g0[r] = acc[r] + bb;
            }
            {
                float acc[4] = {};
                gemv4(acc, H + r0 * 256, 256, 256, Whh + 256 + c, 768);
                float bb = p.gbhh[a * 768 + 256 + c];
#pragma unroll
                for (int r = 0; r < 4; ++r) g1[r] = acc[r] + bb;
            }
            {
                float acc[4] = {};
                gemv4(acc, H + r0 * 256, 256, 256, Whh + 512 + c, 768);
                float bb = p.gbhh[a * 768 + 512 + c];
#pragma unroll
                for (int r = 0; r < 4; ++r) g2[r] = acc[r] + bb;
            }
            float i0[4] = {}, i1[4] = {}, i2[4] = {};
            gemv4(i0, Zp + r0 * 64, 64, 64, Wih + 2 * 768 + c, 768);
            gemv4(i1, Zp + r0 * 64, 64, 64, Wih + 2 * 768 + 256 + c, 768);
            gemv4(i2, Zp + r0 * 64, 64, 64, Wih + 2 * 768 + 512 + c, 768);
            float b0 = p.gbih[a * 768 + c];
            float b1 = p.gbih[a * 768 + 256 + c];
            float b2 = p.gbih[a * 768 + 512 + c];
            float wx00 = Wih[c], wx01 = Wih[768 + c];
            float wx10 = Wih[256 + c], wx11 = Wih[768 + 256 + c];
            float wx20 = Wih[512 + c], wx21 = Wih[768 + 512 + c];
#pragma unroll
            for (int r = 0; r < 4; ++r) {
                int row = row0 + r0 + r;
                float x0 = p.data[(t + 1) * (NB * YD) + row * YD + a * 2];
                float x1 = p.data[(t + 1) * (NB * YD) + row * YD + a * 2 + 1];
                float gi0 = i0[r] + b0 + x0 * wx00 + x1 * wx01;
                float gi1 = i1[r] + b1 + x0 * wx10 + x1 * wx11;
                float gi2 = i2[r] + b2 + x0 * wx20 + x1 * wx21;
                float rr = sigm(gi0 + g0[r]);
                float uu = sigm(gi1 + g1[r]);
                float nn = tanhf(gi2 + rr * g2[r]);
                D[(r0 + r) * 256 + c] = (1.f - uu) * nn + uu * H[(r0 + r) * 256 + c];
            }
        }
        __syncthreads();
        // ---- S11: H <- D ----
#pragma unroll
        for (int r = 0; r < 4; ++r) H[(r0 + r) * 256 + c] = D[(r0 + r) * 256 + c];
        __syncthreads();
    }
    if (tid == 0) {
        atomicAdd(&p.accd[0], bAcc[0]);
        atomicAdd(&p.accd[1], bAcc[1]);
    }
}

extern "C" void kernel_launch(void* const* d_in, const int* in_sizes, int n_in, void* d_out,
                              int out_size, void* d_ws, size_t ws_size, hipStream_t stream) {
    Prm p;
    p.data = (const float*)d_in[0];
    p.macro = (const int*)d_in[1];
    p.eps = (const float*)d_in[2];
    p.enc_W1 = (const float*)d_in[3];
    p.enc_b1 = (const float*)d_in[4];
    p.enc_W2 = (const float*)d_in[5];
    p.enc_b2 = (const float*)d_in[6];
    p.encm_W = (const float*)d_in[7];
    p.encm_b = (const float*)d_in[8];
    p.encs_W = (const float*)d_in[9];
    p.encs_b = (const float*)d_in[10];
    p.pri_W1 = (const float*)d_in[11];
    p.pri_b1 = (const float*)d_in[12];
    p.pri_W2 = (const float*)d_in[13];
    p.pri_b2 = (const float*)d_in[14];
    p.prim_W = (const float*)d_in[15];
    p.prim_b = (const float*)d_in[16];
    p.pris_W = (const float*)d_in[17];
    p.pris_b = (const float*)d_in[18];
    p.dec_W1 = (const float*)d_in[19];
    p.dec_b1 = (const float*)d_in[20];
    p.dec_W2 = (const float*)d_in[21];
    p.dec_b2 = (const float*)d_in[22];
    p.decm_W = (const float*)d_in[23];
    p.decm_b = (const float*)d_in[24];
    p.decs_W = (const float*)d_in[25];
    p.decs_b = (const float*)d_in[26];
    p.gWih = (const float*)d_in[27];
    p.gbih = (const float*)d_in[28];
    p.gWhh = (const float*)d_in[29];
    p.gbhh = (const float*)d_in[30];
    p.accd = (double*)d_ws;

    kzero<<<1, 64, 0, stream>>>(p.accd);
    kmain<<<160, 512, 0, stream>>>(p);
    kfinal<<<1, 64, 0, stream>>>(p.accd, (float*)d_out);
}